// Round 12
// baseline (200.139 us; speedup 1.0000x reference)
//
// PointNet++ FP: three_nn + three_interpolate + pointwise MLP(384->256->128)
// Round 20: 32KB-total LDS via exact overlay; q-form scan restored.
// r19 post-mortem: (512,6) fixed the spill catastrophe but dist3 (no |q|^2)
// doubled scan VALU (VALUBusy 52%, wall 94.5 > r17's 88) and ~15MB residual
// scratch remained. r17 (88us) = best. This round = r17's cheap scan +
// r18's conflict fixes + ONE-ROUND occupancy, at 32KB:
//  * SoA stage sx/sy/sz/sq (8KB each, q=|q|^2 from prep) granule-swizzled
//    G^((G>>2)&3) -> dist = 3 fma (r17 form, selection-exact since r10);
//    phase-3 group bases spread across banks (r18 fix).
//  * EXACT OVERLAY: wave w's sx/sy reads cover bytes [w*1024,(w+1)*1024) ==
//    sdv/siv's wave-w slice. sdv overlays sx, siv overlays sy: each wave
//    writes its slice AFTER its own reads (program order); cross-wave fold
//    reads after the barrier. Scan region = 32KB, no separate sd/si.
//  * MLP region 32KB (r18/r19-verified): Xs_interp[64][256] -> L1a ->
//    stage skip[64][128] over dead half -> L1b -> Y1 overlay -> L2.
//  * Total LDS 32768 -> 4 blocks/CU (wave-slot limited), grid 1024 in ONE
//    round, 32 waves/CU. __launch_bounds__(512,6) (the safe cap: (512,8)
//    spilled 2x: r11, r18).
// SPILL TRIPWIRE: WRITE_SIZE must stay <=45MB; >50MB = scratch -> revert.
// Online-hierarchical scan (r15-r17, verified): per 8-cand group fmin tree
// -> (gmin,gid) insert; exact rescan of 3 winning groups (superset theorem).
// MFMA 16x16x32 bf16 layouts (learn_hip m89/m120 verified):
//   A: [m=lane&15][k=(lane>>4)*8+j]   B: [k=(lane>>4)*8+j][n=lane&15]
//   D: [row=(lane>>4)*4+reg][col=lane&15]
#include <hip/hip_runtime.h>

typedef __bf16 bf16_t;
typedef bf16_t bf16x2_t __attribute__((ext_vector_type(2)));
typedef bf16_t bf16x4_t __attribute__((ext_vector_type(4)));
typedef bf16_t bf16x8_t __attribute__((ext_vector_type(8)));
typedef float floatx4_t __attribute__((ext_vector_type(4)));

constexpr int B_ = 8, N_ = 8192, M_ = 2048;
constexpr int C1 = 128, C2 = 256;
constexpr int K1 = 384, N1 = 256, N2 = 128;

// ws layout (bytes)
constexpr size_t WS_W1T   = 0;         // bf16  [256][384]  = 196608 B
constexpr size_t WS_W2T   = 196608;    // bf16  [128][256]  =  65536 B
constexpr size_t WS_XYZ2P = 262144;    // float4[8*2048]    = 262144 B

// ---------------------------------------------------------------- prep ----
__global__ __launch_bounds__(256) void prep_kernel(
    const float* __restrict__ W1, const float* __restrict__ W2,
    const float* __restrict__ xyz2,
    bf16_t* __restrict__ W1T, bf16_t* __restrict__ W2T,
    float4* __restrict__ xyz2p) {
  int bid = blockIdx.x, tid = threadIdx.x;
  if (bid < 384) {                       // W1 [384][256] -> W1T [256][384]
    int t = bid * 256 + tid;             // 98304 elems
    int n = t / K1, k = t - n * K1;
    W1T[t] = (bf16_t)W1[k * N1 + n];
  } else if (bid < 512) {                // W2 [256][128] -> W2T [128][256]
    int t = (bid - 384) * 256 + tid;     // 32768 elems
    int n = t / N1, k = t - n * N1;
    W2T[t] = (bf16_t)W2[k * N2 + n];
  } else {                               // xyz2 -> float4{x,y,z,|q|^2}
    int t = (bid - 512) * 256 + tid;     // 16384 elems
    const float* p = xyz2 + (size_t)t * 3;
    float x = p[0], y = p[1], z = p[2];
    xyz2p[t] = make_float4(x, y, z, x * x + y * y + z * z);
  }
}

// ---------------------------------------------- fused nn+interp+MLP -------
// 1024 blocks x 512 threads; block owns 64 points of batch b = bi&7 (XCD-local
// points2/xyz2p in that XCD's L2). Wave w = candidate chunk of 256.
__global__ __launch_bounds__(512, 6) void fp_fused_kernel(
    const float* __restrict__ xyz1, const float4* __restrict__ xyz2p,
    const float* __restrict__ points1, const float* __restrict__ points2,
    const bf16_t* __restrict__ W1T, const float* __restrict__ b1,
    const bf16_t* __restrict__ W2T, const float* __restrict__ b2,
    float* __restrict__ out) {
  // LDS map (32KB total):
  //  scan: sx/sdv [0,8K)  sy/siv [8K,16K)  sz [16K,24K)  sq [24K,32K)
  //        (sdv/siv overlay sx/sy: wave w's slice [w*1024,(w+1)*1024) is
  //         exactly wave w's read region -- write-after-own-read safe)
  //  mlp : Xs_interp [64][256] bf16 swz [0,32K); skip [64][128] bf16 swz
  //        [0,16K) after L1a; Y1 [64][256] bf16 swz [0,32K)
  __shared__ __align__(16) char smem[32768];

  int bi = blockIdx.x;
  int b = bi & 7;                  // batch -> XCD (round-robin)
  int base = (bi >> 3) * 64;       // tile within batch (0..127)
  int tid = threadIdx.x;
  int wave = __builtin_amdgcn_readfirstlane(tid >> 6);  // 0..7
  int lane = tid & 63;
  size_t bN = (size_t)b * N_ + base;

  float*  sx  = (float*)smem;              // [2048] granule-swizzled
  float*  sy  = (float*)(smem + 8192);
  float*  sz  = (float*)(smem + 16384);
  float*  sq  = (float*)(smem + 24576);
  float4* sdv = (float4*)smem;             // [8][64] overlay on sx
  int4*   siv = (int4*)(smem + 8192);      // [8][64] overlay on sy

  float w0, w1, w2;                // blend weights (lane = point)
  int   i0, i1, i2;                // top-3 indices (lane = point)

  // ===== Stage xyz2p -> SoA LDS (32KB). Thread t owns granule t (cands
  // 4t..4t+3); 64B coalesced global read; granule-swizzled b128 writes. ====
  {
    const float4* src = xyz2p + b * M_;
    float4 c0 = src[tid * 4 + 0], c1 = src[tid * 4 + 1];
    float4 c2 = src[tid * 4 + 2], c3 = src[tid * 4 + 3];
    int s = tid ^ ((tid >> 2) & 3);
    *(float4*)(sx + s * 4) = make_float4(c0.x, c1.x, c2.x, c3.x);
    *(float4*)(sy + s * 4) = make_float4(c0.y, c1.y, c2.y, c3.y);
    *(float4*)(sz + s * 4) = make_float4(c0.z, c1.z, c2.z, c3.z);
    *(float4*)(sq + s * 4) = make_float4(c0.w, c1.w, c2.w, c3.w);
  }
  __syncthreads();

  // ===== Phase S: three_nn, online-hierarchical, SoA-LDS-fed ==============
  // wave = chunk of 256 cands (granules wave*64..wave*64+63), lane = point.
  {
    const float* p1 = xyz1 + (bN + lane) * 3;
    float x = p1[0], y = p1[1], z = p1[2];
    float sq1 = x * x + y * y + z * z;
    float m2x = -2.0f * x, m2y = -2.0f * y, m2z = -2.0f * z;

    auto dist = [&](float qx, float qy, float qz, float qq) {
      return fmaf(m2x, qx, fmaf(m2y, qy, fmaf(m2z, qz, qq)));
    };

    // top-3 group-mins (6 regs)
    float t0 = 1e30f, t1 = 1e30f, t2 = 1e30f;
    int   g0 = 0, g1 = 0, g2 = 0;
    auto insG = [&](float d, int g) {       // branchless, strict <
      bool l0 = d < t0, l1 = d < t1, l2 = d < t2;
      float n0 = fminf(t0, d);
      float n1 = __builtin_amdgcn_fmed3f(d, t0, t1);
      float n2 = __builtin_amdgcn_fmed3f(d, t1, t2);
      int u1 = l0 ? g0 : g;
      int u2 = l1 ? g1 : g;
      g0 = l0 ? g : g0;
      g1 = l1 ? u1 : g1;
      g2 = l2 ? u2 : g2;
      t0 = n0; t1 = n1; t2 = n2;
    };

    int gw = wave << 5;                     // first group of this chunk
#pragma unroll 1
    for (int g = 0; g < 32; ++g) {
      int G0 = (gw + g) << 1;               // even granule of group
      int sA = G0 ^ ((G0 >> 2) & 3);
      int G1 = G0 + 1;
      int sB = G1 ^ ((G1 >> 2) & 3);
      float4 xa = *(float4*)(sx + sA * 4), xb = *(float4*)(sx + sB * 4);
      float4 ya = *(float4*)(sy + sA * 4), yb = *(float4*)(sy + sB * 4);
      float4 za = *(float4*)(sz + sA * 4), zb = *(float4*)(sz + sB * 4);
      float4 qa = *(float4*)(sq + sA * 4), qb = *(float4*)(sq + sB * 4);
      float d0 = dist(xa.x, ya.x, za.x, qa.x), d1 = dist(xa.y, ya.y, za.y, qa.y);
      float d2 = dist(xa.z, ya.z, za.z, qa.z), d3 = dist(xa.w, ya.w, za.w, qa.w);
      float d4 = dist(xb.x, yb.x, zb.x, qb.x), d5 = dist(xb.y, yb.y, zb.y, qb.y);
      float d6 = dist(xb.z, yb.z, zb.z, qb.z), d7 = dist(xb.w, yb.w, zb.w, qb.w);
      float gm = fminf(fminf(fminf(d0, d1), fminf(d2, d3)),
                       fminf(fminf(d4, d5), fminf(d6, d7)));
      insG(gm, g);
    }

    // sort winning (local) groups ascending: ref tie-break order
    int ga = min(g0, min(g1, g2));
    int gc = max(g0, max(g1, g2));
    int gb = g0 + g1 + g2 - ga - gc;

    // ---- Phase 3: exact rescan of the 3 winning groups (24 cands) ----
    float s0 = 1e30f, s1 = 1e30f, s2 = 1e30f;
    int   a0 = 0, a1 = 0, a2 = 0;
    auto procIdx = [&](float d, int jj) {
      bool l0 = d < s0, l1 = d < s1, l2 = d < s2;
      float n0v = fminf(s0, d);
      float n1v = __builtin_amdgcn_fmed3f(d, s0, s1);
      float n2v = __builtin_amdgcn_fmed3f(d, s1, s2);
      int u1 = l0 ? a0 : jj;               // carry into slot1
      int u2 = l1 ? a1 : jj;               // carry into slot2
      a0 = l0 ? jj : a0;
      a1 = l1 ? u1 : a1;
      a2 = l2 ? u2 : a2;
      s0 = n0v; s1 = n1v; s2 = n2v;
    };
    auto scanGroup = [&](int gg) {          // per-lane divergent LDS reads
      int G0 = (gw + gg) << 1;
      int sA = G0 ^ ((G0 >> 2) & 3);
      int G1 = G0 + 1;
      int sB = G1 ^ ((G1 >> 2) & 3);
      float4 xa = *(float4*)(sx + sA * 4), xb = *(float4*)(sx + sB * 4);
      float4 ya = *(float4*)(sy + sA * 4), yb = *(float4*)(sy + sB * 4);
      float4 za = *(float4*)(sz + sA * 4), zb = *(float4*)(sz + sB * 4);
      float4 qa = *(float4*)(sq + sA * 4), qb = *(float4*)(sq + sB * 4);
      int j8 = (gw + gg) << 3;              // global candidate base
      procIdx(dist(xa.x, ya.x, za.x, qa.x), j8 + 0);
      procIdx(dist(xa.y, ya.y, za.y, qa.y), j8 + 1);
      procIdx(dist(xa.z, ya.z, za.z, qa.z), j8 + 2);
      procIdx(dist(xa.w, ya.w, za.w, qa.w), j8 + 3);
      procIdx(dist(xb.x, yb.x, zb.x, qb.x), j8 + 4);
      procIdx(dist(xb.y, yb.y, zb.y, qb.y), j8 + 5);
      procIdx(dist(xb.z, yb.z, zb.z, qb.z), j8 + 6);
      procIdx(dist(xb.w, yb.w, zb.w, qb.w), j8 + 7);
    };
    scanGroup(ga); scanGroup(gb); scanGroup(gc);

    // write partials into wave-own slice (overlays own read region; all
    // reads above are in program order before these writes)
    sdv[wave * 64 + lane] = make_float4(s0 + sq1, s1 + sq1, s2 + sq1, 0.0f);
    siv[wave * 64 + lane] = make_int4(a0, a1, a2, 0);
  }
  __syncthreads();

  // ===== Fold: every lane folds its point's 8 chunk-partials (redundant
  // across waves -> no serialization; stored d2 is true distance). ========
  {
    float4 d0 = sdv[lane];  int4 x0 = siv[lane];
    float t0 = d0.x, t1 = d0.y, t2 = d0.z;
    int   a0 = x0.x, a1 = x0.y, a2 = x0.z;
    auto ins = [&](float d, int j) {
      if (d < t2) {
        if (d < t1) {
          t2 = t1; a2 = a1;
          if (d < t0) { t1 = t0; a1 = a0; t0 = d; a0 = j; }
          else        { t1 = d;  a1 = j; }
        } else { t2 = d; a2 = j; }
      }
    };
#pragma unroll
    for (int c = 1; c < 8; ++c) {
      float4 dd = sdv[c * 64 + lane];  int4 xx = siv[c * 64 + lane];
      ins(dd.x, xx.x); ins(dd.y, xx.y); ins(dd.z, xx.z);
    }
    float e0 = fmaxf(t0, 1e-10f), e1 = fmaxf(t1, 1e-10f), e2 = fmaxf(t2, 1e-10f);
    float r0 = 1.0f / e0, r1 = 1.0f / e1, r2 = 1.0f / e2;
    float rs = 1.0f / (r0 + r1 + r2);
    w0 = r0 * rs; w1 = r1 * rs; w2 = r2 * rs;
    i0 = a0; i1 = a1; i2 = a2;
  }
  __syncthreads();   // scan regions dead; Xs_interp about to overlay

  // ===== Phase A: gather -> Xs_interp [64][256] bf16 swizzled =============
#pragma unroll 2
  for (int i = 0; i < 8; ++i) {
    int p = wave * 8 + i;
    int j0 = __shfl(i0, p), j1 = __shfl(i1, p), j2 = __shfl(i2, p);
    float u0 = __shfl(w0, p), u1 = __shfl(w1, p), u2 = __shfl(w2, p);
    const float* g0 = points2 + ((size_t)b * M_ + j0) * C2 + lane * 4;
    const float* g1 = points2 + ((size_t)b * M_ + j1) * C2 + lane * 4;
    const float* g2 = points2 + ((size_t)b * M_ + j2) * C2 + lane * 4;
    float4 a0 = *(const float4*)g0;
    float4 a1 = *(const float4*)g1;
    float4 a2 = *(const float4*)g2;
    bf16x4_t v;
    v[0] = (bf16_t)(u0 * a0.x + u1 * a1.x + u2 * a2.x);
    v[1] = (bf16_t)(u0 * a0.y + u1 * a1.y + u2 * a2.y);
    v[2] = (bf16_t)(u0 * a0.z + u1 * a1.z + u2 * a2.z);
    v[3] = (bf16_t)(u0 * a0.w + u1 * a1.w + u2 * a2.w);
    int off = (p << 9) + ((lane * 8) ^ (i << 4));     // (p&7)==i
    *(bf16x4_t*)(smem + off) = v;
  }
  __syncthreads();

  int q = lane >> 4, r = lane & 15;
  int rs8 = (r & 7) << 4;            // row-swizzle XOR (rows r,16+r,32+r,48+r)

  // ---- Layer 1a: interp K=0..255 from Xs_interp; wave owns 32 cols
  floatx4_t acc[4][2] = {};
  int cw = wave * 32;
  const bf16_t* wq0 = W1T + (size_t)(cw +      r) * K1;
  const bf16_t* wq1 = W1T + (size_t)(cw + 16 + r) * K1;
  for (int kk = 0; kk < 8; ++kk) {
    int k0 = kk * 32 + q * 8;
    int co = (k0 << 1) ^ rs8;
    bf16x8_t a0 = *(const bf16x8_t*)(smem + ((     r) << 9) + co);
    bf16x8_t a1 = *(const bf16x8_t*)(smem + ((16 + r) << 9) + co);
    bf16x8_t a2 = *(const bf16x8_t*)(smem + ((32 + r) << 9) + co);
    bf16x8_t a3 = *(const bf16x8_t*)(smem + ((48 + r) << 9) + co);
    bf16x8_t bb0 = *(const bf16x8_t*)(wq0 + k0);
    bf16x8_t bb1 = *(const bf16x8_t*)(wq1 + k0);
    acc[0][0] = __builtin_amdgcn_mfma_f32_16x16x32_bf16(a0, bb0, acc[0][0], 0, 0, 0);
    acc[1][0] = __builtin_amdgcn_mfma_f32_16x16x32_bf16(a1, bb0, acc[1][0], 0, 0, 0);
    acc[2][0] = __builtin_amdgcn_mfma_f32_16x16x32_bf16(a2, bb0, acc[2][0], 0, 0, 0);
    acc[3][0] = __builtin_amdgcn_mfma_f32_16x16x32_bf16(a3, bb0, acc[3][0], 0, 0, 0);
    acc[0][1] = __builtin_amdgcn_mfma_f32_16x16x32_bf16(a0, bb1, acc[0][1], 0, 0, 0);
    acc[1][1] = __builtin_amdgcn_mfma_f32_16x16x32_bf16(a1, bb1, acc[1][1], 0, 0, 0);
    acc[2][1] = __builtin_amdgcn_mfma_f32_16x16x32_bf16(a2, bb1, acc[2][1], 0, 0, 0);
    acc[3][1] = __builtin_amdgcn_mfma_f32_16x16x32_bf16(a3, bb1, acc[3][1], 0, 0, 0);
  }
  __syncthreads();   // all waves done with Xs_interp[0,16K)

  // ---- stage skip: points1 -> [64][128] bf16 @ [0,16K), 256B rows, swz
#pragma unroll 2
  for (int t = 0; t < 8; ++t) {
    int e = tid + t * 512;                  // 0..4095
    int row = e >> 6, pair = e & 63;        // 64 rows x 64 float2
    float2 s = *(const float2*)(points1 + (bN + row) * C1 + pair * 2);
    bf16x2_t v2; v2[0] = (bf16_t)s.x; v2[1] = (bf16_t)s.y;
    int off = (row << 8) + ((pair << 2) ^ ((row & 7) << 4));
    *(bf16x2_t*)(smem + off) = v2;
  }
  __syncthreads();

  // ---- Layer 1b: skip K=256..383 from skip buffer
  for (int kk2 = 0; kk2 < 4; ++kk2) {
    int l = kk2 * 32 + q * 8;               // local col 0..127
    int co = (l << 1) ^ rs8;
    bf16x8_t a0 = *(const bf16x8_t*)(smem + ((     r) << 8) + co);
    bf16x8_t a1 = *(const bf16x8_t*)(smem + ((16 + r) << 8) + co);
    bf16x8_t a2 = *(const bf16x8_t*)(smem + ((32 + r) << 8) + co);
    bf16x8_t a3 = *(const bf16x8_t*)(smem + ((48 + r) << 8) + co);
    int k0 = 256 + l;
    bf16x8_t bb0 = *(const bf16x8_t*)(wq0 + k0);
    bf16x8_t bb1 = *(const bf16x8_t*)(wq1 + k0);
    acc[0][0] = __builtin_amdgcn_mfma_f32_16x16x32_bf16(a0, bb0, acc[0][0], 0, 0, 0);
    acc[1][0] = __builtin_amdgcn_mfma_f32_16x16x32_bf16(a1, bb0, acc[1][0], 0, 0, 0);
    acc[2][0] = __builtin_amdgcn_mfma_f32_16x16x32_bf16(a2, bb0, acc[2][0], 0, 0, 0);
    acc[3][0] = __builtin_amdgcn_mfma_f32_16x16x32_bf16(a3, bb0, acc[3][0], 0, 0, 0);
    acc[0][1] = __builtin_amdgcn_mfma_f32_16x16x32_bf16(a0, bb1, acc[0][1], 0, 0, 0);
    acc[1][1] = __builtin_amdgcn_mfma_f32_16x16x32_bf16(a1, bb1, acc[1][1], 0, 0, 0);
    acc[2][1] = __builtin_amdgcn_mfma_f32_16x16x32_bf16(a2, bb1, acc[2][1], 0, 0, 0);
    acc[3][1] = __builtin_amdgcn_mfma_f32_16x16x32_bf16(a3, bb1, acc[3][1], 0, 0, 0);
  }
  __syncthreads();   // skip region dead only when ALL waves finished L1b

  // bias + relu -> Y1 [64][256] bf16 @ [0,32K), 512B rows, same swizzle
#pragma unroll
  for (int ct = 0; ct < 2; ++ct) {
    int nn = cw + ct * 16 + r;
    float bias = b1[nn];
#pragma unroll
    for (int mt = 0; mt < 4; ++mt) {
#pragma unroll
      for (int reg = 0; reg < 4; ++reg) {
        int m = mt * 16 + q * 4 + reg;
        int off = (m << 9) + ((nn << 1) ^ ((m & 7) << 4));
        *(bf16_t*)(smem + off) = (bf16_t)fmaxf(acc[mt][ct][reg] + bias, 0.0f);
      }
    }
  }
  __syncthreads();

  // ---- Layer 2: [64 x 256] x [256 x 128] -> out, wave owns 16 cols
  floatx4_t acc2[4] = {};
  const bf16_t* vq = W2T + (size_t)(wave * 16 + r) * N1;
  for (int kk = 0; kk < 8; ++kk) {
    int k0 = kk * 32 + q * 8;
    int co = (k0 << 1) ^ rs8;
    bf16x8_t a0 = *(const bf16x8_t*)(smem + ((     r) << 9) + co);
    bf16x8_t a1 = *(const bf16x8_t*)(smem + ((16 + r) << 9) + co);
    bf16x8_t a2 = *(const bf16x8_t*)(smem + ((32 + r) << 9) + co);
    bf16x8_t a3 = *(const bf16x8_t*)(smem + ((48 + r) << 9) + co);
    bf16x8_t bb = *(const bf16x8_t*)(vq + k0);
    acc2[0] = __builtin_amdgcn_mfma_f32_16x16x32_bf16(a0, bb, acc2[0], 0, 0, 0);
    acc2[1] = __builtin_amdgcn_mfma_f32_16x16x32_bf16(a1, bb, acc2[1], 0, 0, 0);
    acc2[2] = __builtin_amdgcn_mfma_f32_16x16x32_bf16(a2, bb, acc2[2], 0, 0, 0);
    acc2[3] = __builtin_amdgcn_mfma_f32_16x16x32_bf16(a3, bb, acc2[3], 0, 0, 0);
  }
  {
    int cc = wave * 16 + r;
    float bias = b2[cc];
#pragma unroll
    for (int mt = 0; mt < 4; ++mt) {
#pragma unroll
      for (int reg = 0; reg < 4; ++reg) {
        int m = mt * 16 + q * 4 + reg;
        out[(bN + m) * N2 + cc] = fmaxf(acc2[mt][reg] + bias, 0.0f);
      }
    }
  }
}

// ----------------------------------------------------------------- launch --
extern "C" void kernel_launch(void* const* d_in, const int* in_sizes, int n_in,
                              void* d_out, int out_size, void* d_ws, size_t ws_size,
                              hipStream_t stream) {
  (void)in_sizes; (void)n_in; (void)out_size; (void)ws_size;
  const float* xyz1    = (const float*)d_in[0];
  const float* xyz2    = (const float*)d_in[1];
  const float* points1 = (const float*)d_in[2];
  const float* points2 = (const float*)d_in[3];
  const float* W1      = (const float*)d_in[4];
  const float* b1      = (const float*)d_in[5];
  const float* W2      = (const float*)d_in[6];
  const float* b2      = (const float*)d_in[7];
  float* out = (float*)d_out;
  char* ws = (char*)d_ws;
  bf16_t* W1T   = (bf16_t*)(ws + WS_W1T);
  bf16_t* W2T   = (bf16_t*)(ws + WS_W2T);
  float4* xyz2p = (float4*)(ws + WS_XYZ2P);

  prep_kernel<<<576, 256, 0, stream>>>(W1, W2, xyz2, W1T, W2T, xyz2p);
  fp_fused_kernel<<<1024, 512, 0, stream>>>(xyz1, xyz2p, points1, points2,
                                            W1T, b1, W2T, b2, out);
}

// Round 13
// 178.277 us; speedup vs baseline: 1.1226x; 1.1226x over previous
//
// PointNet++ FP: three_nn + three_interpolate + pointwise MLP(384->256->128)
// Round 21: r17 (verified best, 88us fused) + phase-3 bank-conflict fix.
// r18/r19/r20 post-mortem: every SoA+skip-split variant produced the same
// poison (FETCH/WRITE +40..80MB hidden scratch/locality loss, occupancy
// capped) -- direction abandoned, reverted to r17 verbatim.
// Single change vs r17: cst candidate ROTATION SWIZZLE
//     cst[(j & ~7) | ((j + (j>>3)) & 7)]   (bijective rotation per 8-block)
// r17's 7.07M LDS bank conflicts come from phase-3 rescan: every lane's
// group base is 128B-aligned -> same bank quadruple -> ~16-way serialize,
// ~24 reads/lane on the scan critical path. With the rotation, read step t
// of group g hits bank-quad (t+g)&7 -> lanes spread across all 8 quads.
// Uniform scan reads are same-address broadcasts (conflict-free) and just
// permuted within their 128B block -> values/insert order BIT-IDENTICAL.
// SPILL TRIPWIRE: WRITE_SIZE ~40MB; >50MB = scratch -> revert.
// Structure (r17, verified): 1024 blocks x 512 thr; stage xyz2p[b] (32KB
// AoS float4 {x,y,z,|q|^2}) -> LDS; online-hierarchical scan (group fmin
// tree -> (gmin,gid) insert -> exact rescan of 3 winning groups, superset
// theorem r14/r16); all-lane redundant fold; Xs[64][384] bf16 XOR-swizzled
// (48KB, skip features LDS-staged in gather); 12-step L1; Y1 overlay; L2.
// MFMA 16x16x32 bf16 layouts (learn_hip m89/m120 verified):
//   A: [m=lane&15][k=(lane>>4)*8+j]   B: [k=(lane>>4)*8+j][n=lane&15]
//   D: [row=(lane>>4)*4+reg][col=lane&15]
#include <hip/hip_runtime.h>

typedef __bf16 bf16_t;
typedef bf16_t bf16x2_t __attribute__((ext_vector_type(2)));
typedef bf16_t bf16x4_t __attribute__((ext_vector_type(4)));
typedef bf16_t bf16x8_t __attribute__((ext_vector_type(8)));
typedef float floatx4_t __attribute__((ext_vector_type(4)));

constexpr int B_ = 8, N_ = 8192, M_ = 2048;
constexpr int C1 = 128, C2 = 256;
constexpr int K1 = 384, N1 = 256, N2 = 128;

// ws layout (bytes)
constexpr size_t WS_W1T   = 0;         // bf16  [256][384]  = 196608 B
constexpr size_t WS_W2T   = 196608;    // bf16  [128][256]  =  65536 B
constexpr size_t WS_XYZ2P = 262144;    // float4[8*2048]    = 262144 B

// ---------------------------------------------------------------- prep ----
__global__ __launch_bounds__(256) void prep_kernel(
    const float* __restrict__ W1, const float* __restrict__ W2,
    const float* __restrict__ xyz2,
    bf16_t* __restrict__ W1T, bf16_t* __restrict__ W2T,
    float4* __restrict__ xyz2p) {
  int bid = blockIdx.x, tid = threadIdx.x;
  if (bid < 384) {                       // W1 [384][256] -> W1T [256][384]
    int t = bid * 256 + tid;             // 98304 elems
    int n = t / K1, k = t - n * K1;
    W1T[t] = (bf16_t)W1[k * N1 + n];
  } else if (bid < 512) {                // W2 [256][128] -> W2T [128][256]
    int t = (bid - 384) * 256 + tid;     // 32768 elems
    int n = t / N1, k = t - n * N1;
    W2T[t] = (bf16_t)W2[k * N2 + n];
  } else {                               // xyz2 -> float4{x,y,z,|q|^2}
    int t = (bid - 512) * 256 + tid;     // 16384 elems
    const float* p = xyz2 + (size_t)t * 3;
    float x = p[0], y = p[1], z = p[2];
    xyz2p[t] = make_float4(x, y, z, x * x + y * y + z * z);
  }
}

// ---------------------------------------------- fused nn+interp+MLP -------
// 1024 blocks x 512 threads; block owns 64 points of batch b = bi&7 (XCD-local
// points2/xyz2p in that XCD's L2). Wave w = candidate chunk of 256.
__global__ __launch_bounds__(512, 6) void fp_fused_kernel(
    const float* __restrict__ xyz1, const float4* __restrict__ xyz2p,
    const float* __restrict__ points1, const float* __restrict__ points2,
    const bf16_t* __restrict__ W1T, const float* __restrict__ b1,
    const bf16_t* __restrict__ W2T, const float* __restrict__ b2,
    float* __restrict__ out) {
  // LDS map. Scan phase: sdv [0,8K), siv [8K,16K), cand stage [16K,48K).
  // Gather..L2 phases: Xs [64][384] bf16 swizzled (48KB) overlays all;
  // Y1 [64][256] overlays Xs after layer 1.
  __shared__ __align__(16) char smem[64 * 768];   // 49152 B

  int bi = blockIdx.x;
  int b = bi & 7;                  // batch -> XCD (round-robin)
  int base = (bi >> 3) * 64;       // tile within batch (0..127)
  int tid = threadIdx.x;
  int wave = __builtin_amdgcn_readfirstlane(tid >> 6);  // 0..7
  int lane = tid & 63;
  size_t bN = (size_t)b * N_ + base;

  float4* sdv = (float4*)smem;             // [8][64] biased top-3 dists
  int4*   siv = (int4*)(smem + 8192);      // [8][64] top-3 indices
  float4* cst = (float4*)(smem + 16384);   // [2048] swizzled xyz2p stage

  // rotation swizzle: bijective within each aligned 8-candidate block;
  // candidate j lives at cst[swz(j)]; bank-quad of elem t of group g is
  // (t+g)&7 -> divergent group reads spread across all 8 quads.
  auto swz = [](int j) { return (j & ~7) | ((j + (j >> 3)) & 7); };

  float w0, w1, w2;                // blend weights (lane = point)
  int   i0, i1, i2;                // top-3 indices (lane = point)

  // ===== Stage xyz2p[b] -> LDS (32KB, coalesced 64B/thread reads) =========
  {
    const float4* src = xyz2p + b * M_;
#pragma unroll
    for (int t = 0; t < 4; ++t) {
      int j = tid + t * 512;
      cst[swz(j)] = src[j];
    }
  }
  __syncthreads();

  // ===== Phase S: three_nn, online-hierarchical, LDS-fed. =================
  // wave = chunk of 256 cands, lane = point; candidate addresses are
  // wave-uniform -> ds_read same-address broadcast (conflict-free).
  {
    const float* p1 = xyz1 + (bN + lane) * 3;
    float x = p1[0], y = p1[1], z = p1[2];
    float sq1 = x * x + y * y + z * z;
    float m2x = -2.0f * x, m2y = -2.0f * y, m2z = -2.0f * z;

    int jb = wave << 8;                    // chunk base (global cand idx)

    auto dist = [&](const float4& qv) {
      return fmaf(m2x, qv.x, fmaf(m2y, qv.y, fmaf(m2z, qv.z, qv.w)));
    };
    auto ld = [&](int jl) { return cst[swz(jb + jl)]; };

    // top-3 group-mins (6 regs, no arrays)
    float t0 = 1e30f, t1 = 1e30f, t2 = 1e30f;
    int   g0 = 0, g1 = 0, g2 = 0;
    auto insG = [&](float d, int g) {       // branchless, strict <
      bool l0 = d < t0, l1 = d < t1, l2 = d < t2;
      float n0 = fminf(t0, d);
      float n1 = __builtin_amdgcn_fmed3f(d, t0, t1);
      float n2 = __builtin_amdgcn_fmed3f(d, t1, t2);
      int u1 = l0 ? g0 : g;
      int u2 = l1 ? g1 : g;
      g0 = l0 ? g : g0;
      g1 = l1 ? u1 : g1;
      g2 = l2 ? u2 : g2;
      t0 = n0; t1 = n1; t2 = n2;
    };

#pragma unroll 2
    for (int g = 0; g < 32; ++g) {
      float4 c0 = ld(g * 8 + 0), c1 = ld(g * 8 + 1);
      float4 c2 = ld(g * 8 + 2), c3 = ld(g * 8 + 3);
      float4 c4 = ld(g * 8 + 4), c5 = ld(g * 8 + 5);
      float4 c6 = ld(g * 8 + 6), c7 = ld(g * 8 + 7);
      float d0 = dist(c0), d1 = dist(c1), d2 = dist(c2), d3 = dist(c3);
      float d4 = dist(c4), d5 = dist(c5), d6 = dist(c6), d7 = dist(c7);
      float gm = fminf(fminf(fminf(d0, d1), fminf(d2, d3)),
                       fminf(fminf(d4, d5), fminf(d6, d7)));
      insG(gm, g);
    }

    // sort winning groups ascending (ref tie-break = ascending-index scan)
    int ga = min(g0, min(g1, g2));
    int gc = max(g0, max(g1, g2));
    int gb = g0 + g1 + g2 - ga - gc;

    // ---- Phase 3: exact rescan of the 3 winning groups (24 cands) ----
    float s0 = 1e30f, s1 = 1e30f, s2 = 1e30f;
    int   a0 = 0, a1 = 0, a2 = 0;
    auto procIdx = [&](const float4& qv, int jj) {
      float d = dist(qv);
      bool l0 = d < s0, l1 = d < s1, l2 = d < s2;
      float n0v = fminf(s0, d);
      float n1v = __builtin_amdgcn_fmed3f(d, s0, s1);
      float n2v = __builtin_amdgcn_fmed3f(d, s1, s2);
      int u1 = l0 ? a0 : jj;               // carry into slot1
      int u2 = l1 ? a1 : jj;               // carry into slot2
      a0 = l0 ? jj : a0;
      a1 = l1 ? u1 : a1;
      a2 = l2 ? u2 : a2;
      s0 = n0v; s1 = n1v; s2 = n2v;
    };
    auto scanGroup = [&](int gg) {          // per-lane divergent LDS reads
      int jg = gg << 3;                     // local base within chunk
#pragma unroll 1
      for (int h = 0; h < 2; ++h) {         // 4 float4 transients max
        float4 c0 = ld(jg + h * 4 + 0), c1 = ld(jg + h * 4 + 1);
        float4 c2 = ld(jg + h * 4 + 2), c3 = ld(jg + h * 4 + 3);
        procIdx(c0, jb + jg + h * 4 + 0);
        procIdx(c1, jb + jg + h * 4 + 1);
        procIdx(c2, jb + jg + h * 4 + 2);
        procIdx(c3, jb + jg + h * 4 + 3);
      }
    };
    scanGroup(ga); scanGroup(gb); scanGroup(gc);

    sdv[wave * 64 + lane] = make_float4(s0 + sq1, s1 + sq1, s2 + sq1, 0.0f);
    siv[wave * 64 + lane] = make_int4(a0, a1, a2, 0);
  }
  __syncthreads();

  // ===== Fold: every lane folds its point's 8 chunk-partials (redundant
  // across waves -> no serialization, results live in regs of lane=point). ===
  {
    float4 d0 = sdv[lane];  int4 x0 = siv[lane];
    float t0 = d0.x, t1 = d0.y, t2 = d0.z;
    int   a0 = x0.x, a1 = x0.y, a2 = x0.z;
    auto ins = [&](float d, int j) {
      if (d < t2) {
        if (d < t1) {
          t2 = t1; a2 = a1;
          if (d < t0) { t1 = t0; a1 = a0; t0 = d; a0 = j; }
          else        { t1 = d;  a1 = j; }
        } else { t2 = d; a2 = j; }
      }
    };
#pragma unroll
    for (int c = 1; c < 8; ++c) {
      float4 dd = sdv[c * 64 + lane];  int4 xx = siv[c * 64 + lane];
      ins(dd.x, xx.x); ins(dd.y, xx.y); ins(dd.z, xx.z);
    }
    float e0 = fmaxf(t0, 1e-10f), e1 = fmaxf(t1, 1e-10f), e2 = fmaxf(t2, 1e-10f);
    float r0 = 1.0f / e0, r1 = 1.0f / e1, r2 = 1.0f / e2;
    float rs = 1.0f / (r0 + r1 + r2);
    w0 = r0 * rs; w1 = r1 * rs; w2 = r2 * rs;
    i0 = a0; i1 = a1; i2 = a2;
  }
  __syncthreads();   // sd/si/cst region about to be overwritten by Xs

  // ===== Phase A: gather -> Xs[64][384] bf16 swizzled ======================
  // wave w fills rows w*8..w*8+7 (interp cols 0..255 + skip cols 256..383).
#pragma unroll 2
  for (int i = 0; i < 8; ++i) {
    int p = wave * 8 + i;
    int j0 = __shfl(i0, p), j1 = __shfl(i1, p), j2 = __shfl(i2, p);
    float u0 = __shfl(w0, p), u1 = __shfl(w1, p), u2 = __shfl(w2, p);
    const float* g0 = points2 + ((size_t)b * M_ + j0) * C2 + lane * 4;
    const float* g1 = points2 + ((size_t)b * M_ + j1) * C2 + lane * 4;
    const float* g2 = points2 + ((size_t)b * M_ + j2) * C2 + lane * 4;
    float4 a0 = *(const float4*)g0;
    float4 a1 = *(const float4*)g1;
    float4 a2 = *(const float4*)g2;
    bf16x4_t v;
    v[0] = (bf16_t)(u0 * a0.x + u1 * a1.x + u2 * a2.x);
    v[1] = (bf16_t)(u0 * a0.y + u1 * a1.y + u2 * a2.y);
    v[2] = (bf16_t)(u0 * a0.z + u1 * a1.z + u2 * a2.z);
    v[3] = (bf16_t)(u0 * a0.w + u1 * a1.w + u2 * a2.w);
    int off = p * 768 + ((lane * 8) ^ (i << 4));      // (p&7)==i
    *(bf16x4_t*)(smem + off) = v;
    const float* pp1 = points1 + (bN + p) * C1 + lane * 2;
    float2 s = *(const float2*)pp1;
    bf16x2_t v2; v2[0] = (bf16_t)s.x; v2[1] = (bf16_t)s.y;
    int off2 = p * 768 + ((512 + lane * 4) ^ (i << 4));
    *(bf16x2_t*)(smem + off2) = v2;
  }
  __syncthreads();

  int q = lane >> 4, r = lane & 15;
  int rs8 = (r & 7) << 4;            // row-swizzle XOR (rows r,16+r,32+r,48+r)

  // ---- Layer 1: [64 x 384] x [384 x 256] -> Y1, wave owns 32 cols
  floatx4_t acc[4][2] = {};
  int cw = wave * 32;
  const bf16_t* wq0 = W1T + (size_t)(cw +      r) * K1;
  const bf16_t* wq1 = W1T + (size_t)(cw + 16 + r) * K1;
  for (int kk = 0; kk < 12; ++kk) {
    int k0 = kk * 32 + q * 8;
    int co = (k0 << 1) ^ rs8;
    bf16x8_t a0 = *(const bf16x8_t*)(smem + (     r) * 768 + co);
    bf16x8_t a1 = *(const bf16x8_t*)(smem + (16 + r) * 768 + co);
    bf16x8_t a2 = *(const bf16x8_t*)(smem + (32 + r) * 768 + co);
    bf16x8_t a3 = *(const bf16x8_t*)(smem + (48 + r) * 768 + co);
    bf16x8_t bb0 = *(const bf16x8_t*)(wq0 + k0);
    bf16x8_t bb1 = *(const bf16x8_t*)(wq1 + k0);
    acc[0][0] = __builtin_amdgcn_mfma_f32_16x16x32_bf16(a0, bb0, acc[0][0], 0, 0, 0);
    acc[1][0] = __builtin_amdgcn_mfma_f32_16x16x32_bf16(a1, bb0, acc[1][0], 0, 0, 0);
    acc[2][0] = __builtin_amdgcn_mfma_f32_16x16x32_bf16(a2, bb0, acc[2][0], 0, 0, 0);
    acc[3][0] = __builtin_amdgcn_mfma_f32_16x16x32_bf16(a3, bb0, acc[3][0], 0, 0, 0);
    acc[0][1] = __builtin_amdgcn_mfma_f32_16x16x32_bf16(a0, bb1, acc[0][1], 0, 0, 0);
    acc[1][1] = __builtin_amdgcn_mfma_f32_16x16x32_bf16(a1, bb1, acc[1][1], 0, 0, 0);
    acc[2][1] = __builtin_amdgcn_mfma_f32_16x16x32_bf16(a2, bb1, acc[2][1], 0, 0, 0);
    acc[3][1] = __builtin_amdgcn_mfma_f32_16x16x32_bf16(a3, bb1, acc[3][1], 0, 0, 0);
  }
  __syncthreads();   // Xs dead only when ALL waves finished layer-1 LDS reads

  // bias + relu -> Y1 [64][256] bf16 (overlays Xs, 512B rows, same swizzle)
#pragma unroll
  for (int ct = 0; ct < 2; ++ct) {
    int nn = cw + ct * 16 + r;
    float bias = b1[nn];
#pragma unroll
    for (int mt = 0; mt < 4; ++mt) {
#pragma unroll
      for (int reg = 0; reg < 4; ++reg) {
        int m = mt * 16 + q * 4 + reg;
        int off = (m << 9) + ((nn << 1) ^ ((m & 7) << 4));
        *(bf16_t*)(smem + off) = (bf16_t)fmaxf(acc[mt][ct][reg] + bias, 0.0f);
      }
    }
  }
  __syncthreads();

  // ---- Layer 2: [64 x 256] x [256 x 128] -> out, wave owns 16 cols
  floatx4_t acc2[4] = {};
  const bf16_t* vq = W2T + (size_t)(wave * 16 + r) * N1;
  for (int kk = 0; kk < 8; ++kk) {
    int k0 = kk * 32 + q * 8;
    int co = (k0 << 1) ^ rs8;
    bf16x8_t a0 = *(const bf16x8_t*)(smem + ((     r) << 9) + co);
    bf16x8_t a1 = *(const bf16x8_t*)(smem + ((16 + r) << 9) + co);
    bf16x8_t a2 = *(const bf16x8_t*)(smem + ((32 + r) << 9) + co);
    bf16x8_t a3 = *(const bf16x8_t*)(smem + ((48 + r) << 9) + co);
    bf16x8_t bb = *(const bf16x8_t*)(vq + k0);
    acc2[0] = __builtin_amdgcn_mfma_f32_16x16x32_bf16(a0, bb, acc2[0], 0, 0, 0);
    acc2[1] = __builtin_amdgcn_mfma_f32_16x16x32_bf16(a1, bb, acc2[1], 0, 0, 0);
    acc2[2] = __builtin_amdgcn_mfma_f32_16x16x32_bf16(a2, bb, acc2[2], 0, 0, 0);
    acc2[3] = __builtin_amdgcn_mfma_f32_16x16x32_bf16(a3, bb, acc2[3], 0, 0, 0);
  }
  {
    int cc = wave * 16 + r;
    float bias = b2[cc];
#pragma unroll
    for (int mt = 0; mt < 4; ++mt) {
#pragma unroll
      for (int reg = 0; reg < 4; ++reg) {
        int m = mt * 16 + q * 4 + reg;
        out[(bN + m) * N2 + cc] = fmaxf(acc2[mt][reg] + bias, 0.0f);
      }
    }
  }
}

// ----------------------------------------------------------------- launch --
extern "C" void kernel_launch(void* const* d_in, const int* in_sizes, int n_in,
                              void* d_out, int out_size, void* d_ws, size_t ws_size,
                              hipStream_t stream) {
  (void)in_sizes; (void)n_in; (void)out_size; (void)ws_size;
  const float* xyz1    = (const float*)d_in[0];
  const float* xyz2    = (const float*)d_in[1];
  const float* points1 = (const float*)d_in[2];
  const float* points2 = (const float*)d_in[3];
  const float* W1      = (const float*)d_in[4];
  const float* b1      = (const float*)d_in[5];
  const float* W2      = (const float*)d_in[6];
  const float* b2      = (const float*)d_in[7];
  float* out = (float*)d_out;
  char* ws = (char*)d_ws;
  bf16_t* W1T   = (bf16_t*)(ws + WS_W1T);
  bf16_t* W2T   = (bf16_t*)(ws + WS_W2T);
  float4* xyz2p = (float4*)(ws + WS_XYZ2P);

  prep_kernel<<<576, 256, 0, stream>>>(W1, W2, xyz2, W1T, W2T, xyz2p);
  fp_fused_kernel<<<1024, 512, 0, stream>>>(xyz1, xyz2p, points1, points2,
                                            W1T, b1, W2T, b2, out);
}